// Round 6
// baseline (160.640 us; speedup 1.0000x reference)
//
#include <hip/hip_runtime.h>
#include <hip/hip_bf16.h>

// Segment-mean over sorted index.
// inp: [N_ROWS, D] fp32, index: [N_ROWS] int32 (sorted), out: [N_SEG, D] fp32.
//
// Pass 1: boundary-scatter -> seg_start[n_seg+1] (first row with index >= s).
// Pass 2: one wave per SPW=4 CONTIGUOUS segments. Bounds seg_start[s0..s0+4]
//         are wave-uniform and contiguous -> scalar-loaded once (1 latency,
//         not 4 dependent ones); the wave's row stream is a contiguous
//         ~4*32 rows run. Lane l covers column quad (l&31), row parity
//         (l>>5); nontemporal float4 loads (input read once, 3.2x L3),
//         unrolled x4; shfl_xor(32) combine; lanes 0..31 write float4 (nt).

typedef float f32x4 __attribute__((ext_vector_type(4)));

#define WAVES_PER_BLOCK 4
#define SPW 4   // segments per wave

__global__ __launch_bounds__(256)
void seg_bounds_kernel(const int* __restrict__ index, int* __restrict__ seg_start,
                       int n_rows, int n_seg) {
    const int r = blockIdx.x * blockDim.x + threadIdx.x;
    if (r >= n_rows) return;
    const int lane = threadIdx.x & 63;
    const int cur  = index[r];
    int prev = __shfl_up(cur, 1, 64);
    if (lane == 0) prev = (r == 0) ? -1 : index[r - 1];
    for (int s = prev + 1; s <= cur; ++s) seg_start[s] = r;
    if (r == n_rows - 1) {
        for (int s = cur + 1; s <= n_seg; ++s) seg_start[s] = n_rows;
    }
}

__global__ __launch_bounds__(256)
void ScatterReduceAggregation_86311662780467_kernel(
    const float* __restrict__ inp,
    const int*   __restrict__ seg_start,
    float*       __restrict__ out,
    int n_seg) {

    const int wave_in_block = threadIdx.x >> 6;
    const int lane          = threadIdx.x & 63;
    int s0 = (blockIdx.x * WAVES_PER_BLOCK + wave_in_block) * SPW;
    if (s0 >= n_seg) return;
    s0 = __builtin_amdgcn_readfirstlane(s0);   // wave-uniform -> scalar bound loads

    // contiguous, wave-uniform bounds: one latency for all SPW+1
    int b[SPW + 1];
    const int nseg_here = (n_seg - s0 < SPW) ? (n_seg - s0) : SPW;
#pragma unroll
    for (int j = 0; j <= SPW; ++j) {
        int idx = s0 + j;
        if (idx > n_seg) idx = n_seg;
        b[j] = seg_start[idx];
    }

    const int half  = lane >> 5;   // row parity this lane covers
    const int quad  = lane & 31;   // which float4 of the row (D=128 -> 32 quads)

    const f32x4* __restrict__ inp4 = reinterpret_cast<const f32x4*>(inp) + quad;
    f32x4* __restrict__ out4 = reinterpret_cast<f32x4*>(out);

#pragma unroll
    for (int j = 0; j < SPW; ++j) {
        if (j >= nseg_here) break;
        const int start = b[j];
        const int end   = b[j + 1];

        f32x4 a0 = (f32x4)0.0f;
        f32x4 a1 = (f32x4)0.0f;
        f32x4 a2 = (f32x4)0.0f;
        f32x4 a3 = (f32x4)0.0f;

        int r = start + half;
        for (; r + 6 < end; r += 8) {
            f32x4 v0 = __builtin_nontemporal_load(&inp4[(size_t)r * 32]);
            f32x4 v1 = __builtin_nontemporal_load(&inp4[(size_t)(r + 2) * 32]);
            f32x4 v2 = __builtin_nontemporal_load(&inp4[(size_t)(r + 4) * 32]);
            f32x4 v3 = __builtin_nontemporal_load(&inp4[(size_t)(r + 6) * 32]);
            a0 += v0;
            a1 += v1;
            a2 += v2;
            a3 += v3;
        }
        for (; r + 2 < end; r += 4) {
            f32x4 v0 = __builtin_nontemporal_load(&inp4[(size_t)r * 32]);
            f32x4 v1 = __builtin_nontemporal_load(&inp4[(size_t)(r + 2) * 32]);
            a0 += v0;
            a1 += v1;
        }
        if (r < end) {
            f32x4 v0 = __builtin_nontemporal_load(&inp4[(size_t)r * 32]);
            a2 += v0;
        }

        a0 += a1;
        a2 += a3;
        a0 += a2;

        // combine the two row-parity halves (lane l <-> lane l^32)
        a0.x += __shfl_xor(a0.x, 32, 64);
        a0.y += __shfl_xor(a0.y, 32, 64);
        a0.z += __shfl_xor(a0.z, 32, 64);
        a0.w += __shfl_xor(a0.w, 32, 64);

        const int cnt = end - start;
        const float inv = (cnt > 0) ? (1.0f / (float)cnt) : 0.0f;

        if (half == 0) {
            f32x4 o = a0 * inv;
            __builtin_nontemporal_store(o, &out4[(size_t)(s0 + j) * 32 + quad]);
        }
    }
}

// Fallback (no workspace): in-kernel binary search, float4 path.
__global__ __launch_bounds__(256)
void seg_mean_search_kernel(
    const float* __restrict__ inp,
    const int*   __restrict__ index,
    float*       __restrict__ out,
    int n_rows, int n_seg) {

    const int wave_in_block = threadIdx.x >> 6;
    const int lane          = threadIdx.x & 63;
    const int seg = blockIdx.x * WAVES_PER_BLOCK + wave_in_block;
    if (seg >= n_seg) return;

    int lo = 0, hi = n_rows;
    while (lo < hi) { int mid = (lo + hi) >> 1; if (index[mid] < seg) lo = mid + 1; else hi = mid; }
    const int start = lo;
    hi = n_rows;
    while (lo < hi) { int mid = (lo + hi) >> 1; if (index[mid] < seg + 1) lo = mid + 1; else hi = mid; }
    const int end = lo;

    const int half = lane >> 5;
    const int quad = lane & 31;
    const f32x4* __restrict__ inp4 = reinterpret_cast<const f32x4*>(inp) + quad;

    f32x4 a0 = (f32x4)0.0f;
    f32x4 a1 = (f32x4)0.0f;
    int r = start + half;
    for (; r + 2 < end; r += 4) {
        f32x4 v0 = inp4[(size_t)r * 32];
        f32x4 v1 = inp4[(size_t)(r + 2) * 32];
        a0 += v0;
        a1 += v1;
    }
    if (r < end) {
        f32x4 v0 = inp4[(size_t)r * 32];
        a0 += v0;
    }
    a0 += a1;
    a0.x += __shfl_xor(a0.x, 32, 64);
    a0.y += __shfl_xor(a0.y, 32, 64);
    a0.z += __shfl_xor(a0.z, 32, 64);
    a0.w += __shfl_xor(a0.w, 32, 64);

    const int cnt = end - start;
    const float inv = (cnt > 0) ? (1.0f / (float)cnt) : 0.0f;
    if (half == 0) {
        f32x4 o = a0 * inv;
        reinterpret_cast<f32x4*>(out)[(size_t)seg * 32 + quad] = o;
    }
}

extern "C" void kernel_launch(void* const* d_in, const int* in_sizes, int n_in,
                              void* d_out, int out_size, void* d_ws, size_t ws_size,
                              hipStream_t stream) {
    const float* inp   = (const float*)d_in[0];
    const int*   index = (const int*)d_in[1];
    float* out = (float*)d_out;

    const int n_rows = in_sizes[1];
    const int d      = in_sizes[0] / n_rows;   // = 128
    const int n_seg  = out_size / d;           // = 50000

    const size_t need = (size_t)(n_seg + 1) * sizeof(int);

    if (ws_size >= need) {
        int* seg_start = (int*)d_ws;
        const int bblocks = (n_rows + 255) / 256;
        seg_bounds_kernel<<<bblocks, 256, 0, stream>>>(index, seg_start, n_rows, n_seg);
        const int segs_per_block = WAVES_PER_BLOCK * SPW;
        const int blocks = (n_seg + segs_per_block - 1) / segs_per_block;
        ScatterReduceAggregation_86311662780467_kernel<<<blocks, 64 * WAVES_PER_BLOCK, 0, stream>>>(
            inp, seg_start, out, n_seg);
    } else {
        const int blocks = (n_seg + WAVES_PER_BLOCK - 1) / WAVES_PER_BLOCK;
        seg_mean_search_kernel<<<blocks, 64 * WAVES_PER_BLOCK, 0, stream>>>(
            inp, index, out, n_rows, n_seg);
    }
}

// Round 7
// 147.413 us; speedup vs baseline: 1.0897x; 1.0897x over previous
//
#include <hip/hip_runtime.h>
#include <hip/hip_bf16.h>

// Segment-mean over sorted index.  (R5 structure — best measured: 148.6 us)
// inp: [N_ROWS, D] fp32, index: [N_ROWS] int32 (sorted), out: [N_SEG, D] fp32.
//
// Pass 1: boundary-scatter -> seg_start[n_seg+1] (first row with index >= s).
// Pass 2: one wave per segment (50K independent waves = the TLP that hides
//         per-segment overhead; R6 showed batching segments per wave HURTS).
//         Lane l covers column quad (l&31), row parity (l>>5). Nontemporal
//         float4 loads (input read exactly once, 3.2x L3), unrolled x4.
//         shfl_xor(32) combine; lanes 0..31 write float4 (nt).

typedef float f32x4 __attribute__((ext_vector_type(4)));

#define WAVES_PER_BLOCK 4

__global__ __launch_bounds__(256)
void seg_bounds_kernel(const int* __restrict__ index, int* __restrict__ seg_start,
                       int n_rows, int n_seg) {
    const int r = blockIdx.x * blockDim.x + threadIdx.x;
    if (r >= n_rows) return;
    const int lane = threadIdx.x & 63;
    const int cur  = __builtin_nontemporal_load(&index[r]);
    int prev = __shfl_up(cur, 1, 64);
    if (lane == 0) prev = (r == 0) ? -1 : index[r - 1];
    for (int s = prev + 1; s <= cur; ++s) seg_start[s] = r;
    if (r == n_rows - 1) {
        for (int s = cur + 1; s <= n_seg; ++s) seg_start[s] = n_rows;
    }
}

__global__ __launch_bounds__(256)
void ScatterReduceAggregation_86311662780467_kernel(
    const float* __restrict__ inp,
    const int*   __restrict__ seg_start,
    float*       __restrict__ out,
    int n_seg) {

    const int wave_in_block = threadIdx.x >> 6;
    const int lane          = threadIdx.x & 63;
    int seg = blockIdx.x * WAVES_PER_BLOCK + wave_in_block;
    if (seg >= n_seg) return;
    seg = __builtin_amdgcn_readfirstlane(seg);   // wave-uniform -> SGPR -> s_load bounds

    const int start = seg_start[seg];
    const int end   = seg_start[seg + 1];

    const int half  = lane >> 5;   // row parity this lane covers
    const int quad  = lane & 31;   // which float4 of the row (D=128 -> 32 quads)

    const f32x4* __restrict__ inp4 = reinterpret_cast<const f32x4*>(inp) + quad;

    f32x4 a0 = (f32x4)0.0f;
    f32x4 a1 = (f32x4)0.0f;
    f32x4 a2 = (f32x4)0.0f;
    f32x4 a3 = (f32x4)0.0f;

    int r = start + half;
    for (; r + 6 < end; r += 8) {
        f32x4 v0 = __builtin_nontemporal_load(&inp4[(size_t)r * 32]);
        f32x4 v1 = __builtin_nontemporal_load(&inp4[(size_t)(r + 2) * 32]);
        f32x4 v2 = __builtin_nontemporal_load(&inp4[(size_t)(r + 4) * 32]);
        f32x4 v3 = __builtin_nontemporal_load(&inp4[(size_t)(r + 6) * 32]);
        a0 += v0;
        a1 += v1;
        a2 += v2;
        a3 += v3;
    }
    for (; r + 2 < end; r += 4) {
        f32x4 v0 = __builtin_nontemporal_load(&inp4[(size_t)r * 32]);
        f32x4 v1 = __builtin_nontemporal_load(&inp4[(size_t)(r + 2) * 32]);
        a0 += v0;
        a1 += v1;
    }
    if (r < end) {
        f32x4 v0 = __builtin_nontemporal_load(&inp4[(size_t)r * 32]);
        a2 += v0;
    }

    a0 += a1;
    a2 += a3;
    a0 += a2;

    // combine the two row-parity halves (lane l <-> lane l^32)
    a0.x += __shfl_xor(a0.x, 32, 64);
    a0.y += __shfl_xor(a0.y, 32, 64);
    a0.z += __shfl_xor(a0.z, 32, 64);
    a0.w += __shfl_xor(a0.w, 32, 64);

    const int cnt = end - start;
    const float inv = (cnt > 0) ? (1.0f / (float)cnt) : 0.0f;

    if (half == 0) {
        f32x4 o = a0 * inv;
        __builtin_nontemporal_store(o, &reinterpret_cast<f32x4*>(out)[(size_t)seg * 32 + quad]);
    }
}

// Fallback (no workspace): in-kernel binary search, float4 path.
__global__ __launch_bounds__(256)
void seg_mean_search_kernel(
    const float* __restrict__ inp,
    const int*   __restrict__ index,
    float*       __restrict__ out,
    int n_rows, int n_seg) {

    const int wave_in_block = threadIdx.x >> 6;
    const int lane          = threadIdx.x & 63;
    const int seg = blockIdx.x * WAVES_PER_BLOCK + wave_in_block;
    if (seg >= n_seg) return;

    int lo = 0, hi = n_rows;
    while (lo < hi) { int mid = (lo + hi) >> 1; if (index[mid] < seg) lo = mid + 1; else hi = mid; }
    const int start = lo;
    hi = n_rows;
    while (lo < hi) { int mid = (lo + hi) >> 1; if (index[mid] < seg + 1) lo = mid + 1; else hi = mid; }
    const int end = lo;

    const int half = lane >> 5;
    const int quad = lane & 31;
    const f32x4* __restrict__ inp4 = reinterpret_cast<const f32x4*>(inp) + quad;

    f32x4 a0 = (f32x4)0.0f;
    f32x4 a1 = (f32x4)0.0f;
    int r = start + half;
    for (; r + 2 < end; r += 4) {
        f32x4 v0 = inp4[(size_t)r * 32];
        f32x4 v1 = inp4[(size_t)(r + 2) * 32];
        a0 += v0;
        a1 += v1;
    }
    if (r < end) {
        f32x4 v0 = inp4[(size_t)r * 32];
        a0 += v0;
    }
    a0 += a1;
    a0.x += __shfl_xor(a0.x, 32, 64);
    a0.y += __shfl_xor(a0.y, 32, 64);
    a0.z += __shfl_xor(a0.z, 32, 64);
    a0.w += __shfl_xor(a0.w, 32, 64);

    const int cnt = end - start;
    const float inv = (cnt > 0) ? (1.0f / (float)cnt) : 0.0f;
    if (half == 0) {
        f32x4 o = a0 * inv;
        reinterpret_cast<f32x4*>(out)[(size_t)seg * 32 + quad] = o;
    }
}

extern "C" void kernel_launch(void* const* d_in, const int* in_sizes, int n_in,
                              void* d_out, int out_size, void* d_ws, size_t ws_size,
                              hipStream_t stream) {
    const float* inp   = (const float*)d_in[0];
    const int*   index = (const int*)d_in[1];
    float* out = (float*)d_out;

    const int n_rows = in_sizes[1];
    const int d      = in_sizes[0] / n_rows;   // = 128
    const int n_seg  = out_size / d;           // = 50000

    const int blocks = (n_seg + WAVES_PER_BLOCK - 1) / WAVES_PER_BLOCK;
    const size_t need = (size_t)(n_seg + 1) * sizeof(int);

    if (ws_size >= need) {
        int* seg_start = (int*)d_ws;
        const int bblocks = (n_rows + 255) / 256;
        seg_bounds_kernel<<<bblocks, 256, 0, stream>>>(index, seg_start, n_rows, n_seg);
        ScatterReduceAggregation_86311662780467_kernel<<<blocks, 64 * WAVES_PER_BLOCK, 0, stream>>>(
            inp, seg_start, out, n_seg);
    } else {
        seg_mean_search_kernel<<<blocks, 64 * WAVES_PER_BLOCK, 0, stream>>>(
            inp, index, out, n_rows, n_seg);
    }
}